// Round 6
// baseline (785.052 us; speedup 1.0000x reference)
//
#include <hip/hip_runtime.h>

static inline int idiv(int a, int b) { return (a + b - 1) / b; }

// ---------------- zero workspace via kernel ----------------
__global__ void k_zero(float4* __restrict__ p, long n4) {
    long t = (long)blockIdx.x * blockDim.x + threadIdx.x;
    long stride = (long)gridDim.x * blockDim.x;
    for (; t < n4; t += stride) p[t] = make_float4(0.f, 0.f, 0.f, 0.f);
}

// ---------------- degree count: deg[dst[e]] += 1 ----------------
__global__ void k_deg(const int* __restrict__ dst, float* __restrict__ deg, int E) {
    int t = blockIdx.x * blockDim.x + threadIdx.x;
    if (t < E) atomicAdd(&deg[dst[t]], 1.0f);
}

// ---------------- deg -> deg^-0.5 in place ----------------
__global__ void k_dinv(float* __restrict__ deg, int n) {
    int t = blockIdx.x * blockDim.x + threadIdx.x;
    if (t < n) {
        float d = deg[t];
        deg[t] = (d > 0.0f) ? rsqrtf(d) : 0.0f;
    }
}

// ---- scatter: tx[d][f] += -(dinv[s]*dinv[d]) * x[s][f] ----
template <int LOGF>
__global__ void k_scatter(const int* __restrict__ src, const int* __restrict__ dst,
                          const float* __restrict__ dinv, const float* __restrict__ xin,
                          float* __restrict__ tx, int E) {
    int t = blockIdx.x * blockDim.x + threadIdx.x;
    int e = t >> LOGF;
    int f = t & ((1 << LOGF) - 1);
    if (e >= E) return;
    int s = src[e], d = dst[e];
    float w = -(dinv[s] * dinv[d]);
    atomicAdd(&tx[((long)d << LOGF) + f], w * xin[((long)s << LOGF) + f]);
}

// ---- layer1 fused: val = relu(x@W0 + tx@W1 + b); hp[cl[n]][j] max= val ----
__global__ void k_cheb1_max(const float* __restrict__ x, const float* __restrict__ tx,
                            const float* __restrict__ W0, const float* __restrict__ W1,
                            const float* __restrict__ b, const int* __restrict__ cl,
                            float* __restrict__ hp, int N) {
    __shared__ float sW0[16 * 32], sW1[16 * 32], sb[32];
    for (int i = threadIdx.x; i < 16 * 32; i += blockDim.x) {
        sW0[i] = W0[i];
        sW1[i] = W1[i];
    }
    if (threadIdx.x < 32) sb[threadIdx.x] = b[threadIdx.x];
    __syncthreads();
    int t = blockIdx.x * blockDim.x + threadIdx.x;
    int n = t >> 5, j = t & 31;
    if (n >= N) return;
    const float* xr = x + (long)n * 16;
    const float* tr = tx + (long)n * 16;
    float acc = sb[j];
#pragma unroll
    for (int k = 0; k < 16; k++) acc += xr[k] * sW0[k * 32 + j] + tr[k] * sW1[k * 32 + j];
    float v = fmaxf(acc, 0.0f);  // >= 0, so int-punned atomicMax on zero-init is exact
    atomicMax((int*)&hp[((long)cl[n] << 5) + j], __float_as_int(v));
}

// ---- layer2 fused: val = relu(hp@W0 + tx@W1 + b); h3[cl[n]][j] max= val ----
__global__ void k_cheb2_max(const float* __restrict__ xp, const float* __restrict__ tx,
                            const float* __restrict__ W0, const float* __restrict__ W1,
                            const float* __restrict__ b, const int* __restrict__ cl,
                            float* __restrict__ h3, int n1) {
    __shared__ float sW0[32 * 64], sW1[32 * 64], sb[64];
    for (int i = threadIdx.x; i < 32 * 64; i += blockDim.x) {
        sW0[i] = W0[i];
        sW1[i] = W1[i];
    }
    if (threadIdx.x < 64) sb[threadIdx.x] = b[threadIdx.x];
    __syncthreads();
    int t = blockIdx.x * blockDim.x + threadIdx.x;
    int n = t >> 6, j = t & 63;
    if (n >= n1) return;
    const float* xr = xp + (long)n * 32;
    const float* tr = tx + (long)n * 32;
    float acc = sb[j];
#pragma unroll
    for (int k = 0; k < 32; k++) acc += xr[k] * sW0[k * 64 + j] + tr[k] * sW1[k * 64 + j];
    float v = fmaxf(acc, 0.0f);
    atomicMax((int*)&h3[((long)cl[n] << 6) + j], __float_as_int(v));
}

// ---------------- per-graph sum + count ----------------
__global__ void k_gsum(const float* __restrict__ h3, const int* __restrict__ batch,
                       float* __restrict__ gsum, float* __restrict__ gcnt, int n2) {
    int t = blockIdx.x * blockDim.x + threadIdx.x;
    int n = t >> 6, f = t & 63;
    if (n >= n2) return;
    int g = batch[n];
    atomicAdd(&gsum[g * 64 + f], h3[t]);
    if (f == 0) atomicAdd(&gcnt[g], 1.0f);
}

// ---------------- fc1: g1 = relu(mean @ fcw1 + fcb1), one block ----------------
__global__ void k_fc1(const float* __restrict__ gsum, const float* __restrict__ gcnt,
                      const float* __restrict__ fcw1, const float* __restrict__ fcb1,
                      float* __restrict__ g1) {
    __shared__ float sg[8 * 64];
    int tid = threadIdx.x;
    if (tid < 512) {
        float c = gcnt[tid >> 6];
        sg[tid] = (c > 0.0f) ? gsum[tid] / c : 0.0f;
    }
    __syncthreads();
    int gi = tid >> 7, j = tid & 127;
    float acc = fcb1[j];
#pragma unroll 8
    for (int k = 0; k < 64; k++) acc += sg[gi * 64 + k] * fcw1[k * 128 + j];
    g1[tid] = fmaxf(acc, 0.0f);
}

// ---------------- fc2: out = g1 @ fcw2 + fcb2, f32 output ----------------
__global__ void k_fc2(const float* __restrict__ g1, const float* __restrict__ fcw2,
                      const float* __restrict__ fcb2, float* __restrict__ out, int OUT) {
    __shared__ float sg[8 * 128];
    for (int i = threadIdx.x; i < 1024; i += blockDim.x) sg[i] = g1[i];
    __syncthreads();
    int o = blockIdx.x * blockDim.x + threadIdx.x;
    if (o >= OUT) return;
    float bias = fcb2[o];
    float acc[8];
#pragma unroll
    for (int gi = 0; gi < 8; gi++) acc[gi] = bias;
    for (int k = 0; k < 128; k++) {
        float w = fcw2[(long)k * OUT + o];
#pragma unroll
        for (int gi = 0; gi < 8; gi++) acc[gi] += sg[gi * 128 + k] * w;
    }
#pragma unroll
    for (int gi = 0; gi < 8; gi++) out[(long)gi * OUT + o] = acc[gi];
}

extern "C" void kernel_launch(void* const* d_in, const int* in_sizes, int n_in,
                              void* d_out, int out_size, void* d_ws, size_t ws_size,
                              hipStream_t stream) {
    const float* x    = (const float*)d_in[0];
    const float* W0a  = (const float*)d_in[1];
    const float* W1a  = (const float*)d_in[2];
    const float* b1   = (const float*)d_in[3];
    const float* W0b  = (const float*)d_in[4];
    const float* W1b  = (const float*)d_in[5];
    const float* b2   = (const float*)d_in[6];
    const float* fcw1 = (const float*)d_in[7];
    const float* fcb1 = (const float*)d_in[8];
    const float* fcw2 = (const float*)d_in[9];
    const float* fcb2 = (const float*)d_in[10];
    const int* ei1    = (const int*)d_in[11];
    const int* cl1    = (const int*)d_in[12];
    const int* ei2    = (const int*)d_in[13];
    const int* cl2    = (const int*)d_in[14];
    const int* b3     = (const int*)d_in[15];

    const int N  = in_sizes[12];        // len(cluster1) = 80000
    const int E1 = in_sizes[11] / 2;
    const int E2 = in_sizes[13] / 2;
    const int n1 = in_sizes[14];        // len(cluster2)
    const int n2 = in_sizes[15];        // len(batch3)
    const int G  = 8;
    const int OUT = out_size / G;       // 20000

    // ---- workspace layout (region reuse, 256B aligned => float4 aligned) ----
    auto rnd = [](size_t b) { return (b + 255) & ~(size_t)255; };
    size_t degB = rnd((size_t)((N > n1) ? N : n1) * 4);
    size_t txB  = rnd((size_t)(((long)N * 16 > (long)n1 * 32) ? (long)N * 16 : (long)n1 * 32) * 4);
    size_t hpB  = rnd((size_t)n1 * 32 * 4);
    size_t h3B  = rnd((size_t)n2 * 64 * 4);
    size_t smlB = rnd((512 + 8 + 1024) * 4);

    char* base = (char*)d_ws;
    float* deg  = (float*)base;
    float* txA  = (float*)(base + degB);
    float* hp   = (float*)(base + degB + txB);
    float* h3   = (float*)(base + degB + txB + hpB);
    float* gsum = (float*)(base + degB + txB + hpB + h3B);
    float* gcnt = gsum + 512;
    float* g1   = gcnt + 8;
    size_t used = degB + txB + hpB + h3B + smlB;
    if (used > ws_size) used = ws_size;  // never touch beyond the allocation

    dim3 B(256);
    // ---- zero everything we use (kernel-based; no memset dependence) ----
    long n4all = (long)(used / 16);
    int gz = idiv((int)((n4all < 1048576) ? n4all : 1048576), 256);
    if (gz < 1) gz = 1;
    if (gz > 4096) gz = 4096;
    k_zero<<<gz, B, 0, stream>>>((float4*)base, n4all);

    // ---- layer 1 ----
    k_deg<<<idiv(E1, 256), B, 0, stream>>>(ei1 + E1, deg, E1);
    k_dinv<<<idiv(N, 256), B, 0, stream>>>(deg, N);
    k_scatter<4><<<idiv(E1 * 16, 256), B, 0, stream>>>(ei1, ei1 + E1, deg, x, txA, E1);
    k_cheb1_max<<<idiv(N * 32, 256), B, 0, stream>>>(x, txA, W0a, W1a, b1, cl1, hp, N);

    // ---- re-zero deg + txA for layer 2 (stream-ordered after cheb1) ----
    long n4l2 = (long)((degB + txB) / 16);
    int gz2 = idiv((int)((n4l2 < 1048576) ? n4l2 : 1048576), 256);
    if (gz2 < 1) gz2 = 1;
    if (gz2 > 4096) gz2 = 4096;
    k_zero<<<gz2, B, 0, stream>>>((float4*)base, n4l2);

    // ---- layer 2 ----
    k_deg<<<idiv(E2, 256), B, 0, stream>>>(ei2 + E2, deg, E2);
    k_dinv<<<idiv(n1, 256), B, 0, stream>>>(deg, n1);
    k_scatter<5><<<idiv(E2 * 32, 256), B, 0, stream>>>(ei2, ei2 + E2, deg, hp, txA, E2);
    k_cheb2_max<<<idiv(n1 * 64, 256), B, 0, stream>>>(hp, txA, W0b, W1b, b2, cl2, h3, n1);

    // ---- readout ----
    k_gsum<<<idiv(n2 * 64, 256), B, 0, stream>>>(h3, b3, gsum, gcnt, n2);
    k_fc1<<<1, 1024, 0, stream>>>(gsum, gcnt, fcw1, fcb1, g1);
    k_fc2<<<idiv(OUT, 256), B, 0, stream>>>(g1, fcw2, fcb2, (float*)d_out, OUT);
}

// Round 7
// 522.557 us; speedup vs baseline: 1.5023x; 1.5023x over previous
//
#include <hip/hip_runtime.h>

static inline int idiv(int a, int b) { return (a + b - 1) / b; }

// ---------------- zero workspace via kernel ----------------
__global__ void k_zero(float4* __restrict__ p, long n4) {
    long t = (long)blockIdx.x * blockDim.x + threadIdx.x;
    long stride = (long)gridDim.x * blockDim.x;
    for (; t < n4; t += stride) p[t] = make_float4(0.f, 0.f, 0.f, 0.f);
}

// ---------------- degree count: deg[dst[e]] += 1 ----------------
__global__ void k_deg(const int* __restrict__ dst, float* __restrict__ deg, int E) {
    int t = blockIdx.x * blockDim.x + threadIdx.x;
    if (t < E) atomicAdd(&deg[dst[t]], 1.0f);
}

// ---------------- deg -> deg^-0.5 in place ----------------
__global__ void k_dinv(float* __restrict__ deg, int n) {
    int t = blockIdx.x * blockDim.x + threadIdx.x;
    if (t < n) {
        float d = deg[t];
        deg[t] = (d > 0.0f) ? rsqrtf(d) : 0.0f;
    }
}

// ---- scatter: tx[d][f] += -(dinv[s]*dinv[d]) * x[s][f] ----
template <int LOGF>
__global__ void k_scatter(const int* __restrict__ src, const int* __restrict__ dst,
                          const float* __restrict__ dinv, const float* __restrict__ xin,
                          float* __restrict__ tx, int E) {
    int t = blockIdx.x * blockDim.x + threadIdx.x;
    int e = t >> LOGF;
    int f = t & ((1 << LOGF) - 1);
    if (e >= E) return;
    int s = src[e], d = dst[e];
    float w = -(dinv[s] * dinv[d]);
    atomicAdd(&tx[((long)d << LOGF) + f], w * xin[((long)s << LOGF) + f]);
}

// ---- layer1 fused: val = relu(x@W0 + tx@W1 + b); hp[cl[n]][j] max= val ----
__global__ void k_cheb1_max(const float* __restrict__ x, const float* __restrict__ tx,
                            const float* __restrict__ W0, const float* __restrict__ W1,
                            const float* __restrict__ b, const int* __restrict__ cl,
                            float* __restrict__ hp, int N) {
    __shared__ float sW0[16 * 32], sW1[16 * 32], sb[32];
    for (int i = threadIdx.x; i < 16 * 32; i += blockDim.x) {
        sW0[i] = W0[i];
        sW1[i] = W1[i];
    }
    if (threadIdx.x < 32) sb[threadIdx.x] = b[threadIdx.x];
    __syncthreads();
    int t = blockIdx.x * blockDim.x + threadIdx.x;
    int n = t >> 5, j = t & 31;
    if (n >= N) return;
    const float* xr = x + (long)n * 16;
    const float* tr = tx + (long)n * 16;
    float acc = sb[j];
#pragma unroll
    for (int k = 0; k < 16; k++) acc += xr[k] * sW0[k * 32 + j] + tr[k] * sW1[k * 32 + j];
    float v = fmaxf(acc, 0.0f);  // >= 0, so int-punned atomicMax on zero-init is exact
    atomicMax((int*)&hp[((long)cl[n] << 5) + j], __float_as_int(v));
}

// ---- layer2 fused: val = relu(hp@W0 + tx@W1 + b); h3[cl[n]][j] max= val ----
__global__ void k_cheb2_max(const float* __restrict__ xp, const float* __restrict__ tx,
                            const float* __restrict__ W0, const float* __restrict__ W1,
                            const float* __restrict__ b, const int* __restrict__ cl,
                            float* __restrict__ h3, int n1) {
    __shared__ float sW0[32 * 64], sW1[32 * 64], sb[64];
    for (int i = threadIdx.x; i < 32 * 64; i += blockDim.x) {
        sW0[i] = W0[i];
        sW1[i] = W1[i];
    }
    if (threadIdx.x < 64) sb[threadIdx.x] = b[threadIdx.x];
    __syncthreads();
    int t = blockIdx.x * blockDim.x + threadIdx.x;
    int n = t >> 6, j = t & 63;
    if (n >= n1) return;
    const float* xr = xp + (long)n * 32;
    const float* tr = tx + (long)n * 32;
    float acc = sb[j];
#pragma unroll
    for (int k = 0; k < 32; k++) acc += xr[k] * sW0[k * 64 + j] + tr[k] * sW1[k * 64 + j];
    float v = fmaxf(acc, 0.0f);
    atomicMax((int*)&h3[((long)cl[n] << 6) + j], __float_as_int(v));
}

// ---- per-graph sum + count: two-stage (LDS partials -> one atomic set per block) ----
__global__ void k_gsum(const float* __restrict__ h3, const int* __restrict__ batch,
                       float* __restrict__ gsum, float* __restrict__ gcnt, int n2) {
    __shared__ float s[8 * 64];
    __shared__ float sc[8];
    for (int i = threadIdx.x; i < 512; i += blockDim.x) s[i] = 0.0f;
    if (threadIdx.x < 8) sc[threadIdx.x] = 0.0f;
    __syncthreads();
    long total = (long)n2 * 64;
    long stride = (long)gridDim.x * blockDim.x;
    for (long t = (long)blockIdx.x * blockDim.x + threadIdx.x; t < total; t += stride) {
        int n = (int)(t >> 6), f = (int)(t & 63);
        int g = batch[n];
        atomicAdd(&s[g * 64 + f], h3[t]);
        if (f == 0) atomicAdd(&sc[g], 1.0f);
    }
    __syncthreads();
    for (int i = threadIdx.x; i < 512; i += blockDim.x) atomicAdd(&gsum[i], s[i]);
    if (threadIdx.x < 8) atomicAdd(&gcnt[threadIdx.x], sc[threadIdx.x]);
}

// ---------------- fc1: g1 = relu(mean @ fcw1 + fcb1), one block ----------------
__global__ void k_fc1(const float* __restrict__ gsum, const float* __restrict__ gcnt,
                      const float* __restrict__ fcw1, const float* __restrict__ fcb1,
                      float* __restrict__ g1) {
    __shared__ float sg[8 * 64];
    int tid = threadIdx.x;
    if (tid < 512) {
        float c = gcnt[tid >> 6];
        sg[tid] = (c > 0.0f) ? gsum[tid] / c : 0.0f;
    }
    __syncthreads();
    int gi = tid >> 7, j = tid & 127;
    float acc = fcb1[j];
#pragma unroll 8
    for (int k = 0; k < 64; k++) acc += sg[gi * 64 + k] * fcw1[k * 128 + j];
    g1[tid] = fmaxf(acc, 0.0f);
}

// ---------------- fc2: out = g1 @ fcw2 + fcb2, f32 output ----------------
__global__ void k_fc2(const float* __restrict__ g1, const float* __restrict__ fcw2,
                      const float* __restrict__ fcb2, float* __restrict__ out, int OUT) {
    __shared__ float sg[8 * 128];
    for (int i = threadIdx.x; i < 1024; i += blockDim.x) sg[i] = g1[i];
    __syncthreads();
    int o = blockIdx.x * blockDim.x + threadIdx.x;
    if (o >= OUT) return;
    float bias = fcb2[o];
    float acc[8];
#pragma unroll
    for (int gi = 0; gi < 8; gi++) acc[gi] = bias;
    for (int k = 0; k < 128; k++) {
        float w = fcw2[(long)k * OUT + o];
#pragma unroll
        for (int gi = 0; gi < 8; gi++) acc[gi] += sg[gi * 128 + k] * w;
    }
#pragma unroll
    for (int gi = 0; gi < 8; gi++) out[(long)gi * OUT + o] = acc[gi];
}

extern "C" void kernel_launch(void* const* d_in, const int* in_sizes, int n_in,
                              void* d_out, int out_size, void* d_ws, size_t ws_size,
                              hipStream_t stream) {
    const float* x    = (const float*)d_in[0];
    const float* W0a  = (const float*)d_in[1];
    const float* W1a  = (const float*)d_in[2];
    const float* b1   = (const float*)d_in[3];
    const float* W0b  = (const float*)d_in[4];
    const float* W1b  = (const float*)d_in[5];
    const float* b2   = (const float*)d_in[6];
    const float* fcw1 = (const float*)d_in[7];
    const float* fcb1 = (const float*)d_in[8];
    const float* fcw2 = (const float*)d_in[9];
    const float* fcb2 = (const float*)d_in[10];
    const int* ei1    = (const int*)d_in[11];
    const int* cl1    = (const int*)d_in[12];
    const int* ei2    = (const int*)d_in[13];
    const int* cl2    = (const int*)d_in[14];
    const int* b3     = (const int*)d_in[15];

    const int N  = in_sizes[12];        // len(cluster1) = 80000
    const int E1 = in_sizes[11] / 2;
    const int E2 = in_sizes[13] / 2;
    const int n1 = in_sizes[14];        // len(cluster2)
    const int n2 = in_sizes[15];        // len(batch3)
    const int G  = 8;
    const int OUT = out_size / G;       // 20000

    // ---- workspace layout (region reuse, 256B aligned => float4 aligned) ----
    auto rnd = [](size_t b) { return (b + 255) & ~(size_t)255; };
    size_t degB = rnd((size_t)((N > n1) ? N : n1) * 4);
    size_t txB  = rnd((size_t)(((long)N * 16 > (long)n1 * 32) ? (long)N * 16 : (long)n1 * 32) * 4);
    size_t hpB  = rnd((size_t)n1 * 32 * 4);
    size_t h3B  = rnd((size_t)n2 * 64 * 4);
    size_t smlB = rnd((512 + 8 + 1024) * 4);

    char* base = (char*)d_ws;
    float* deg  = (float*)base;
    float* txA  = (float*)(base + degB);
    float* hp   = (float*)(base + degB + txB);
    float* h3   = (float*)(base + degB + txB + hpB);
    float* gsum = (float*)(base + degB + txB + hpB + h3B);
    float* gcnt = gsum + 512;
    float* g1   = gcnt + 8;
    size_t used = degB + txB + hpB + h3B + smlB;
    if (used > ws_size) used = ws_size;  // never touch beyond the allocation

    dim3 B(256);
    // ---- zero everything we use (kernel-based; no memset dependence) ----
    long n4all = (long)(used / 16);
    int gz = idiv((int)((n4all < 1048576) ? n4all : 1048576), 256);
    if (gz < 1) gz = 1;
    if (gz > 4096) gz = 4096;
    k_zero<<<gz, B, 0, stream>>>((float4*)base, n4all);

    // ---- layer 1 ----
    k_deg<<<idiv(E1, 256), B, 0, stream>>>(ei1 + E1, deg, E1);
    k_dinv<<<idiv(N, 256), B, 0, stream>>>(deg, N);
    k_scatter<4><<<idiv(E1 * 16, 256), B, 0, stream>>>(ei1, ei1 + E1, deg, x, txA, E1);
    k_cheb1_max<<<idiv(N * 32, 256), B, 0, stream>>>(x, txA, W0a, W1a, b1, cl1, hp, N);

    // ---- re-zero deg + txA for layer 2 (stream-ordered after cheb1) ----
    long n4l2 = (long)((degB + txB) / 16);
    int gz2 = idiv((int)((n4l2 < 1048576) ? n4l2 : 1048576), 256);
    if (gz2 < 1) gz2 = 1;
    if (gz2 > 4096) gz2 = 4096;
    k_zero<<<gz2, B, 0, stream>>>((float4*)base, n4l2);

    // ---- layer 2 ----
    k_deg<<<idiv(E2, 256), B, 0, stream>>>(ei2 + E2, deg, E2);
    k_dinv<<<idiv(n1, 256), B, 0, stream>>>(deg, n1);
    k_scatter<5><<<idiv(E2 * 32, 256), B, 0, stream>>>(ei2, ei2 + E2, deg, hp, txA, E2);
    k_cheb2_max<<<idiv(n1 * 64, 256), B, 0, stream>>>(hp, txA, W0b, W1b, b2, cl2, h3, n1);

    // ---- readout: two-stage reduction (fixes 274us same-address atomic serialization) ----
    int gb = idiv(n2 * 64, 256);
    if (gb > 256) gb = 256;
    k_gsum<<<gb, B, 0, stream>>>(h3, b3, gsum, gcnt, n2);
    k_fc1<<<1, 1024, 0, stream>>>(gsum, gcnt, fcw1, fcb1, g1);
    k_fc2<<<idiv(OUT, 256), B, 0, stream>>>(g1, fcw2, fcb2, (float*)d_out, OUT);
}